// Round 1
// baseline (1014.157 us; speedup 1.0000x reference)
//
#include <hip/hip_runtime.h>
#include <cstdint>
#include <cstddef>

// Problem constants (from reference): N=100000, E=300000, B=50000, L=4,
// D_EMB=128, D_HID=64, H=8.  All inputs fp32 / int32; output fp32 [B, 512].

__device__ __forceinline__ unsigned enc_f(float f) {
    unsigned u = __float_as_uint(f);
    return (u & 0x80000000u) ? ~u : (u | 0x80000000u);
}
__device__ __forceinline__ float dec_f(unsigned u) {
    return (u & 0x80000000u) ? __uint_as_float(u & 0x7fffffffu) : __uint_as_float(~u);
}

// ---------------------------------------------------------------------------
// K_w: transpose W_i,W_p into WT[K][d]; K<128 -> W_i[d][K], K>=128 -> W_p[d][K-128]
__global__ __launch_bounds__(256) void k_transpose(
    const float* __restrict__ Wi, const float* __restrict__ Wp, float* __restrict__ WT) {
    int t = blockIdx.x * 256 + threadIdx.x;   // 256*64 = 16384 total
    if (t >= 256 * 64) return;
    int d = t & 63, K = t >> 6;
    float v = (K < 128) ? Wi[d * 128 + K] : Wp[d * 128 + (K - 128)];
    WT[K * 64 + d] = v;
}

// ---------------------------------------------------------------------------
// K1: edata[e,d] = sum_k (x0+x3)[k]*W_i[d,k] + (x1+x2)[k]*W_p[d,k]
// Tiled GEMM: 64 edges x 64 outputs per block, K=256 in 4 chunks of 64.
__global__ __launch_bounds__(256) void k_edata(
    const int* __restrict__ mp, const float* __restrict__ feat,
    const float* __restrict__ WT, float* __restrict__ edata, int E) {
    __shared__ float sAT[64 * 64];  // [k][e]
    __shared__ float sBT[64 * 64];  // [k][d]
    int t = threadIdx.x;
    int eb = blockIdx.x * 64;
    int el = t >> 2;                 // staging: edge 0..63
    int e = eb + el;
    int ec = e < E ? e : E - 1;
    int kq = (t & 3) * 16;           // staging: 16 k-values
    int tx = t & 15, ty = t >> 4;    // micro: d-group, edge-group

    float acc[4][4];
#pragma unroll
    for (int i = 0; i < 4; ++i)
#pragma unroll
        for (int j = 0; j < 4; ++j) acc[i][j] = 0.f;

    int4 rows = *(const int4*)(mp + (size_t)ec * 4);

    for (int kk = 0; kk < 4; ++kk) {
        int K0 = kk * 64;
        int rA, rB;
        if (K0 < 128) { rA = rows.x; rB = rows.w; }  // x0 + x3 -> W_i
        else          { rA = rows.y; rB = rows.z; }  // x1 + x2 -> W_p
        int kg = (K0 & 127) + kq;
        const float* pA = feat + (size_t)rA * 128 + kg;
        const float* pB = feat + (size_t)rB * 128 + kg;
#pragma unroll
        for (int i = 0; i < 16; i += 4) {
            float4 a = *(const float4*)(pA + i);
            float4 b = *(const float4*)(pB + i);
            sAT[(kq + i + 0) * 64 + el] = a.x + b.x;
            sAT[(kq + i + 1) * 64 + el] = a.y + b.y;
            sAT[(kq + i + 2) * 64 + el] = a.z + b.z;
            sAT[(kq + i + 3) * 64 + el] = a.w + b.w;
        }
        const float4* src = (const float4*)(WT + K0 * 64);
        float4* dst4 = (float4*)sBT;
#pragma unroll
        for (int i = 0; i < 4; ++i) dst4[t + i * 256] = src[t + i * 256];
        __syncthreads();
#pragma unroll 8
        for (int k = 0; k < 64; ++k) {
            float4 av = *(const float4*)&sAT[k * 64 + ty * 4];
            float4 bv = *(const float4*)&sBT[k * 64 + tx * 4];
            acc[0][0] += av.x * bv.x; acc[0][1] += av.x * bv.y; acc[0][2] += av.x * bv.z; acc[0][3] += av.x * bv.w;
            acc[1][0] += av.y * bv.x; acc[1][1] += av.y * bv.y; acc[1][2] += av.y * bv.z; acc[1][3] += av.y * bv.w;
            acc[2][0] += av.z * bv.x; acc[2][1] += av.z * bv.y; acc[2][2] += av.z * bv.z; acc[2][3] += av.z * bv.w;
            acc[3][0] += av.w * bv.x; acc[3][1] += av.w * bv.y; acc[3][2] += av.w * bv.z; acc[3][3] += av.w * bv.w;
        }
        __syncthreads();
    }
#pragma unroll
    for (int jj = 0; jj < 4; ++jj) {
        int ee = eb + ty * 4 + jj;
        if (ee < E) {
            float4 v = make_float4(acc[jj][0], acc[jj][1], acc[jj][2], acc[jj][3]);
            *(float4*)&edata[(size_t)ee * 64 + tx * 4] = v;
        }
    }
}

// ---------------------------------------------------------------------------
// K2: logits[e,h] = lrelu( sum_i (edata[e]·attn[i]) * W_th[h,i] ); atomicMax per (dst,h)
__global__ __launch_bounds__(256) void k_logits(
    const float* __restrict__ edata, const float* __restrict__ attn,
    const float* __restrict__ Wth, const int* __restrict__ edge_dst,
    float* __restrict__ logits, unsigned* __restrict__ maxu, int E) {
    int wid = blockIdx.x * 4 + (threadIdx.x >> 6);
    int lane = threadIdx.x & 63;
    if (wid >= E) return;
    float ed = edata[(size_t)wid * 64 + lane];
    float r[8];
#pragma unroll
    for (int i = 0; i < 8; ++i) {
        float p = ed * attn[i * 64 + lane];
#pragma unroll
        for (int o = 32; o > 0; o >>= 1) p += __shfl_xor(p, o);
        r[i] = p;  // full sum in all lanes (butterfly)
    }
    if (lane < 8) {
        float l = 0.f;
#pragma unroll
        for (int i = 0; i < 8; ++i) l += r[i] * Wth[lane * 8 + i];
        l = l > 0.f ? l : 0.01f * l;
        logits[(size_t)wid * 8 + lane] = l;
        int dst = edge_dst[wid];
        atomicMax(&maxu[dst * 8 + lane], enc_f(l));
    }
}

// ---------------------------------------------------------------------------
// K3: ex = exp(l - m[dst]); den[dst,h] += ex  (in-place over logits)
__global__ __launch_bounds__(256) void k_expsum(
    float* __restrict__ logits, const unsigned* __restrict__ maxu,
    float* __restrict__ den, const int* __restrict__ edge_dst, int total) {
    int idx = blockIdx.x * 256 + threadIdx.x;
    if (idx >= total) return;
    int e = idx >> 3, h = idx & 7;
    int dst = edge_dst[e];
    float m = dec_f(maxu[dst * 8 + h]);
    float ex = __expf(logits[idx] - m);
    logits[idx] = ex;
    atomicAdd(&den[dst * 8 + h], ex);
}

// ---------------------------------------------------------------------------
// K4: node_ft[dst, h*64+d] += edata[e,d] * (ex/den)[e,h]
__global__ __launch_bounds__(256) void k_aggregate(
    const float* __restrict__ edata, const float* __restrict__ exv,
    const float* __restrict__ den, const int* __restrict__ edge_dst,
    float* __restrict__ node_ft, int E) {
    int wid = blockIdx.x * 4 + (threadIdx.x >> 6);
    int lane = threadIdx.x & 63;
    if (wid >= E) return;
    int dst = edge_dst[wid];
    float ed = edata[(size_t)wid * 64 + lane];
    float av = 0.f;
    if (lane < 8) av = exv[(size_t)wid * 8 + lane] / den[dst * 8 + lane];
    float* base = node_ft + (size_t)dst * 512;
#pragma unroll
    for (int h = 0; h < 8; ++h) {
        float ah = __shfl(av, h);
        atomicAdd(base + h * 64 + lane, ed * ah);
    }
}

// ---------------------------------------------------------------------------
// K5: per-batch-row gate partials: g_b[h] = sum_d node_ft[n,h,d]*Wg[d]
__global__ __launch_bounds__(256) void k_gatepart(
    const float* __restrict__ node_ft, const int* __restrict__ batch_nodes,
    const float* __restrict__ Wg, float* __restrict__ gate_part, int B) {
    int wid = blockIdx.x * 4 + (threadIdx.x >> 6);
    int lane = threadIdx.x & 63;
    if (wid >= B) return;
    int n = batch_nodes[wid];
    float wg = Wg[lane];
    const float* base = node_ft + (size_t)n * 512;
    float myv = 0.f;
#pragma unroll
    for (int h = 0; h < 8; ++h) {
        float p = base[h * 64 + lane] * wg;
#pragma unroll
        for (int o = 32; o > 0; o >>= 1) p += __shfl_xor(p, o);
        if (lane == h) myv = p;
    }
    if (lane < 8) atomicAdd(&gate_part[(blockIdx.x & 255) * 8 + lane], myv);
}

// K6: gate[h] = sum(gate_part)/B + b_gate
__global__ __launch_bounds__(64) void k_gatefinal(
    const float* __restrict__ gate_part, const float* __restrict__ b_gate,
    float* __restrict__ gate, int B) {
    int t = threadIdx.x;
    if (t < 8) {
        float s = 0.f;
        for (int i = 0; i < 256; ++i) s += gate_part[i * 8 + t];
        gate[t] = s / (float)B + b_gate[0];
    }
}

// ---------------------------------------------------------------------------
// K7: out[b, h*64+d] = node_ft[batch_nodes[b], h*64+d] * gate[h]
__global__ __launch_bounds__(256) void k_output(
    const float* __restrict__ node_ft, const int* __restrict__ batch_nodes,
    const float* __restrict__ gate, float* __restrict__ out, int B) {
    int idx = blockIdx.x * 256 + threadIdx.x;  // one float4 each
    int total = B * 128;
    if (idx >= total) return;
    int b = idx >> 7;       // 128 float4 per row
    int rem4 = idx & 127;   // float4 index within row
    int h = rem4 >> 4;      // 16 float4 per head
    int n = batch_nodes[b];
    float4 v = *(const float4*)(node_ft + (size_t)n * 512 + rem4 * 4);
    float g = gate[h];
    float4 o;
    o.x = v.x * g; o.y = v.y * g; o.z = v.z * g; o.w = v.w * g;
    *(float4*)(out + (size_t)idx * 4) = o;
}

// ---------------------------------------------------------------------------
extern "C" void kernel_launch(void* const* d_in, const int* in_sizes, int n_in,
                              void* d_out, int out_size, void* d_ws, size_t ws_size,
                              hipStream_t stream) {
    const int*   batch_nodes = (const int*)d_in[0];
    const int*   mp          = (const int*)d_in[1];
    const int*   edge_dst    = (const int*)d_in[2];
    const float* feat        = (const float*)d_in[3];
    const float* W_i         = (const float*)d_in[4];
    const float* W_p         = (const float*)d_in[5];
    const float* attn        = (const float*)d_in[6];
    const float* W_th        = (const float*)d_in[7];
    const float* W_gate      = (const float*)d_in[8];
    const float* b_gate      = (const float*)d_in[9];
    float* out = (float*)d_out;

    const int B = in_sizes[0];
    const int E = in_sizes[2];
    const int N = in_sizes[3] / 128;

    // workspace carve (all offsets 256B-aligned)
    char* w = (char*)d_ws;
    float* WT = (float*)w;          w += 256 * 64 * sizeof(float);        // 64 KB
    float* edata = (float*)w;       w += (size_t)E * 64 * sizeof(float);  // 76.8 MB
    float* logits = (float*)w;      w += (size_t)E * 8 * sizeof(float);   // 9.6 MB
    unsigned* maxu = (unsigned*)w;  w += (size_t)N * 8 * sizeof(unsigned);// 3.2 MB
    float* den = (float*)w;         w += (size_t)N * 8 * sizeof(float);   // 3.2 MB
    float* node_ft = (float*)w;     w += (size_t)N * 512 * sizeof(float); // 204.8 MB
    float* gate_part = (float*)w;   w += 256 * 8 * sizeof(float);
    float* gate = (float*)w;        w += 256;

    // zero-init accumulators (ws is poisoned 0xAA before every launch)
    hipMemsetAsync(maxu, 0, (size_t)N * 8 * sizeof(unsigned), stream);
    hipMemsetAsync(den, 0, (size_t)N * 8 * sizeof(float), stream);
    hipMemsetAsync(node_ft, 0, (size_t)N * 512 * sizeof(float), stream);
    hipMemsetAsync(gate_part, 0, 256 * 8 * sizeof(float), stream);

    k_transpose<<<64, 256, 0, stream>>>(W_i, W_p, WT);

    int nb1 = (E + 63) / 64;
    k_edata<<<nb1, 256, 0, stream>>>(mp, feat, WT, edata, E);

    int nb2 = (E + 3) / 4;
    k_logits<<<nb2, 256, 0, stream>>>(edata, attn, W_th, edge_dst, logits, maxu, E);

    int total3 = E * 8;
    k_expsum<<<(total3 + 255) / 256, 256, 0, stream>>>(logits, maxu, den, edge_dst, total3);

    k_aggregate<<<nb2, 256, 0, stream>>>(edata, logits, den, edge_dst, node_ft, E);

    int nb5 = (B + 3) / 4;
    k_gatepart<<<nb5, 256, 0, stream>>>(node_ft, batch_nodes, W_gate, gate_part, B);

    k_gatefinal<<<1, 64, 0, stream>>>(gate_part, b_gate, gate, B);

    int total7 = B * 128;
    k_output<<<(total7 + 255) / 256, 256, 0, stream>>>(node_ft, batch_nodes, gate, out, B);
}

// Round 2
// 400.962 us; speedup vs baseline: 2.5293x; 2.5293x over previous
//
#include <hip/hip_runtime.h>
#include <cstdint>
#include <cstddef>

// N=100000, E=300000, B=50000, L=4, D_EMB=128, D_HID=64, H=8. fp32 in/out.
// Strategy (R2): batch-flag nodes -> CSR of incoming edges for flagged dst only
// (Ec ~ 0.39*E) -> compacted edata GEMM + logits -> per-node gather softmax +
// aggregation (no atomics on node_ft, write-once, no memset) with fused gate dot.

// ---------------------------------------------------------------------------
// transpose W_i,W_p into WT[K][d]; K<128 -> W_i[d][K], K>=128 -> W_p[d][K-128]
__global__ __launch_bounds__(256) void k_transpose(
    const float* __restrict__ Wi, const float* __restrict__ Wp, float* __restrict__ WT) {
    int t = blockIdx.x * 256 + threadIdx.x;
    if (t >= 256 * 64) return;
    int d = t & 63, K = t >> 6;
    float v = (K < 128) ? Wi[d * 128 + K] : Wp[d * 128 + (K - 128)];
    WT[K * 64 + d] = v;
}

// mult[n] = multiplicity of n in batch_nodes (doubles as "flagged" marker)
__global__ __launch_bounds__(256) void k_count(
    const int* __restrict__ batch_nodes, int* __restrict__ mult, int B) {
    int i = blockIdx.x * 256 + threadIdx.x;
    if (i < B) atomicAdd(&mult[batch_nodes[i]], 1);
}

// count[d] = #incoming edges for flagged d
__global__ __launch_bounds__(256) void k_hist(
    const int* __restrict__ edge_dst, const int* __restrict__ mult,
    int* __restrict__ count, int E) {
    int e = blockIdx.x * 256 + threadIdx.x;
    if (e >= E) return;
    int d = edge_dst[e];
    if (mult[d] > 0) atomicAdd(&count[d], 1);
}

// 3-kernel exclusive scan of count[0..N) -> offsets[0..N]; offsets[N]=total=Ec
__global__ __launch_bounds__(256) void k_scan1(
    const int* __restrict__ count, int* __restrict__ excl, int* __restrict__ partials, int N) {
    __shared__ int lds[256];
    int t = threadIdx.x, i = blockIdx.x * 256 + t;
    int c = (i < N) ? count[i] : 0;
    lds[t] = c; __syncthreads();
    for (int o = 1; o < 256; o <<= 1) {
        int v = (t >= o) ? lds[t - o] : 0;
        __syncthreads(); lds[t] += v; __syncthreads();
    }
    if (i < N) excl[i] = lds[t] - c;
    if (t == 255) partials[blockIdx.x] = lds[255];
}
__global__ __launch_bounds__(512) void k_scan2(
    const int* __restrict__ partials, int* __restrict__ blockoff,
    int* __restrict__ offsets, int nb, int N) {
    __shared__ int lds[512];
    int t = threadIdx.x;
    int c = (t < nb) ? partials[t] : 0;
    lds[t] = c; __syncthreads();
    for (int o = 1; o < 512; o <<= 1) {
        int v = (t >= o) ? lds[t - o] : 0;
        __syncthreads(); lds[t] += v; __syncthreads();
    }
    if (t < nb) blockoff[t] = lds[t] - c;
    if (t == nb - 1) offsets[N] = lds[t];
}
__global__ __launch_bounds__(256) void k_scan3(
    const int* __restrict__ excl, const int* __restrict__ blockoff,
    int* __restrict__ offsets, int* __restrict__ cursor, int N) {
    int i = blockIdx.x * 256 + threadIdx.x;
    if (i < N) {
        int o = excl[i] + blockoff[i >> 8];
        offsets[i] = o; cursor[i] = o;
    }
}

// csr[pos] = original edge id, grouped by dst (flagged only)
__global__ __launch_bounds__(256) void k_scatter(
    const int* __restrict__ edge_dst, const int* __restrict__ mult,
    int* __restrict__ cursor, int* __restrict__ csr, int E) {
    int e = blockIdx.x * 256 + threadIdx.x;
    if (e >= E) return;
    int d = edge_dst[e];
    if (mult[d] > 0) {
        int pos = atomicAdd(&cursor[d], 1);
        csr[pos] = e;
    }
}

// ---------------------------------------------------------------------------
// edata[i,d] for csr slot i (e=csr[i]): (x0+x3)@Wi.T + (x1+x2)@Wp.T
// Tiled: 64 slots x 64 outputs per block, K=256 in 4 chunks of 64.
__global__ __launch_bounds__(256) void k_edata(
    const int* __restrict__ csr, const int* __restrict__ pEc,
    const int* __restrict__ mp, const float* __restrict__ feat,
    const float* __restrict__ WT, float* __restrict__ edata) {
    int Ec = *pEc;
    int eb = blockIdx.x * 64;
    if (eb >= Ec) return;
    __shared__ float sAT[64 * 64];  // [k][slot]
    __shared__ float sBT[64 * 64];  // [k][d]
    int t = threadIdx.x;
    int el = t >> 2;
    int g = eb + el;
    int gc = g < Ec ? g : Ec - 1;
    int e = csr[gc];
    int kq = (t & 3) * 16;
    int tx = t & 15, ty = t >> 4;

    float acc[4][4];
#pragma unroll
    for (int i = 0; i < 4; ++i)
#pragma unroll
        for (int j = 0; j < 4; ++j) acc[i][j] = 0.f;

    int4 rows = *(const int4*)(mp + (size_t)e * 4);

    for (int kk = 0; kk < 4; ++kk) {
        int K0 = kk * 64;
        int rA, rB;
        if (K0 < 128) { rA = rows.x; rB = rows.w; }
        else          { rA = rows.y; rB = rows.z; }
        int kg = (K0 & 127) + kq;
        const float* pA = feat + (size_t)rA * 128 + kg;
        const float* pB = feat + (size_t)rB * 128 + kg;
#pragma unroll
        for (int i = 0; i < 16; i += 4) {
            float4 a = *(const float4*)(pA + i);
            float4 b = *(const float4*)(pB + i);
            sAT[(kq + i + 0) * 64 + el] = a.x + b.x;
            sAT[(kq + i + 1) * 64 + el] = a.y + b.y;
            sAT[(kq + i + 2) * 64 + el] = a.z + b.z;
            sAT[(kq + i + 3) * 64 + el] = a.w + b.w;
        }
        const float4* src = (const float4*)(WT + K0 * 64);
        float4* dst4 = (float4*)sBT;
#pragma unroll
        for (int i = 0; i < 4; ++i) dst4[t + i * 256] = src[t + i * 256];
        __syncthreads();
#pragma unroll 8
        for (int k = 0; k < 64; ++k) {
            float4 av = *(const float4*)&sAT[k * 64 + ty * 4];
            float4 bv = *(const float4*)&sBT[k * 64 + tx * 4];
            acc[0][0] += av.x * bv.x; acc[0][1] += av.x * bv.y; acc[0][2] += av.x * bv.z; acc[0][3] += av.x * bv.w;
            acc[1][0] += av.y * bv.x; acc[1][1] += av.y * bv.y; acc[1][2] += av.y * bv.z; acc[1][3] += av.y * bv.w;
            acc[2][0] += av.z * bv.x; acc[2][1] += av.z * bv.y; acc[2][2] += av.z * bv.z; acc[2][3] += av.z * bv.w;
            acc[3][0] += av.w * bv.x; acc[3][1] += av.w * bv.y; acc[3][2] += av.w * bv.z; acc[3][3] += av.w * bv.w;
        }
        __syncthreads();
    }
#pragma unroll
    for (int jj = 0; jj < 4; ++jj) {
        int ee = eb + ty * 4 + jj;
        if (ee < Ec) {
            float4 v = make_float4(acc[jj][0], acc[jj][1], acc[jj][2], acc[jj][3]);
            *(float4*)&edata[(size_t)ee * 64 + tx * 4] = v;
        }
    }
}

// ---------------------------------------------------------------------------
// logits[i,h] = lrelu( sum_j (edata[i]·attn[j]) * W_th[h,j] )  (csr-ordered)
__global__ __launch_bounds__(256) void k_logits(
    const float* __restrict__ edata, const float* __restrict__ attn,
    const float* __restrict__ Wth, const int* __restrict__ pEc,
    float* __restrict__ logits) {
    int Ec = *pEc;
    int wid = blockIdx.x * 4 + (threadIdx.x >> 6);
    int lane = threadIdx.x & 63;
    if (wid >= Ec) return;
    float ed = edata[(size_t)wid * 64 + lane];
    float r[8];
#pragma unroll
    for (int i = 0; i < 8; ++i) {
        float p = ed * attn[i * 64 + lane];
#pragma unroll
        for (int o = 32; o > 0; o >>= 1) p += __shfl_xor(p, o);
        r[i] = p;
    }
    if (lane < 8) {
        float l = 0.f;
#pragma unroll
        for (int i = 0; i < 8; ++i) l += r[i] * Wth[lane * 8 + i];
        l = l > 0.f ? l : 0.01f * l;
        logits[(size_t)wid * 8 + lane] = l;
    }
}

// ---------------------------------------------------------------------------
// Per flagged node: softmax over its csr range + weighted accumulation.
// One wave per node; lane = d. Write node_ft once; fused gate partial dot.
__global__ __launch_bounds__(256) void k_node_agg(
    const float* __restrict__ edata, const float* __restrict__ logits,
    const int* __restrict__ offsets, const int* __restrict__ mult,
    const float* __restrict__ Wg, float* __restrict__ node_ft,
    float* __restrict__ gate_part, int N) {
    int n = blockIdx.x * 4 + (threadIdx.x >> 6);
    int lane = threadIdx.x & 63;
    if (n >= N) return;
    int m = mult[n];
    if (m == 0) return;
    int beg = offsets[n], end = offsets[n + 1];

    float mx[8];
#pragma unroll
    for (int h = 0; h < 8; ++h) mx[h] = -1e30f;
    for (int j = beg; j < end; ++j) {
        const float4* lp = (const float4*)(logits + (size_t)j * 8);
        float4 l0 = lp[0], l1 = lp[1];
        mx[0] = fmaxf(mx[0], l0.x); mx[1] = fmaxf(mx[1], l0.y);
        mx[2] = fmaxf(mx[2], l0.z); mx[3] = fmaxf(mx[3], l0.w);
        mx[4] = fmaxf(mx[4], l1.x); mx[5] = fmaxf(mx[5], l1.y);
        mx[6] = fmaxf(mx[6], l1.z); mx[7] = fmaxf(mx[7], l1.w);
    }
    float den[8];
#pragma unroll
    for (int h = 0; h < 8; ++h) den[h] = 0.f;
    for (int j = beg; j < end; ++j) {
        const float4* lp = (const float4*)(logits + (size_t)j * 8);
        float4 l0 = lp[0], l1 = lp[1];
        den[0] += __expf(l0.x - mx[0]); den[1] += __expf(l0.y - mx[1]);
        den[2] += __expf(l0.z - mx[2]); den[3] += __expf(l0.w - mx[3]);
        den[4] += __expf(l1.x - mx[4]); den[5] += __expf(l1.y - mx[5]);
        den[6] += __expf(l1.z - mx[6]); den[7] += __expf(l1.w - mx[7]);
    }
    float rden[8];
#pragma unroll
    for (int h = 0; h < 8; ++h) rden[h] = (end > beg) ? 1.f / den[h] : 0.f;

    float acc[8];
#pragma unroll
    for (int h = 0; h < 8; ++h) acc[h] = 0.f;
    for (int j = beg; j < end; ++j) {
        const float4* lp = (const float4*)(logits + (size_t)j * 8);
        float4 l0 = lp[0], l1 = lp[1];
        float ed = edata[(size_t)j * 64 + lane];
        acc[0] += __expf(l0.x - mx[0]) * rden[0] * ed;
        acc[1] += __expf(l0.y - mx[1]) * rden[1] * ed;
        acc[2] += __expf(l0.z - mx[2]) * rden[2] * ed;
        acc[3] += __expf(l0.w - mx[3]) * rden[3] * ed;
        acc[4] += __expf(l1.x - mx[4]) * rden[4] * ed;
        acc[5] += __expf(l1.y - mx[5]) * rden[5] * ed;
        acc[6] += __expf(l1.z - mx[6]) * rden[6] * ed;
        acc[7] += __expf(l1.w - mx[7]) * rden[7] * ed;
    }

    float* base = node_ft + (size_t)n * 512;
#pragma unroll
    for (int h = 0; h < 8; ++h) base[h * 64 + lane] = acc[h];

    // gate partial: dot(node_ft[n,h,:], Wg) per head, weighted by multiplicity
    float wg = Wg[lane];
    float myg = 0.f;
#pragma unroll
    for (int h = 0; h < 8; ++h) {
        float p = acc[h] * wg;
#pragma unroll
        for (int o = 32; o > 0; o >>= 1) p += __shfl_xor(p, o);
        if (lane == h) myg = p;
    }
    if (lane < 8)
        atomicAdd(&gate_part[(blockIdx.x & 1023) * 8 + lane], (float)m * myg);
}

// gate[h] = sum(gate_part)/B + b_gate
__global__ __launch_bounds__(256) void k_gatefinal(
    const float* __restrict__ gate_part, const float* __restrict__ b_gate,
    float* __restrict__ gate, int B) {
    __shared__ float lds[256];
    int t = threadIdx.x;
    int h = t & 7, g = t >> 3;        // 32 groups x 8 heads
    float s = 0.f;
    for (int b = g; b < 1024; b += 32) s += gate_part[b * 8 + h];
    lds[t] = s; __syncthreads();
    if (t < 8) {
        float tot = 0.f;
        for (int gg = 0; gg < 32; ++gg) tot += lds[gg * 8 + t];
        gate[t] = tot / (float)B + b_gate[0];
    }
}

// out[b, h*64+d] = node_ft[batch_nodes[b], h*64+d] * gate[h]
__global__ __launch_bounds__(256) void k_output(
    const float* __restrict__ node_ft, const int* __restrict__ batch_nodes,
    const float* __restrict__ gate, float* __restrict__ out, int B) {
    int idx = blockIdx.x * 256 + threadIdx.x;
    int total = B * 128;
    if (idx >= total) return;
    int b = idx >> 7;
    int rem4 = idx & 127;
    int h = rem4 >> 4;
    int n = batch_nodes[b];
    float4 v = *(const float4*)(node_ft + (size_t)n * 512 + rem4 * 4);
    float g = gate[h];
    float4 o;
    o.x = v.x * g; o.y = v.y * g; o.z = v.z * g; o.w = v.w * g;
    *(float4*)(out + (size_t)idx * 4) = o;
}

// ---------------------------------------------------------------------------
extern "C" void kernel_launch(void* const* d_in, const int* in_sizes, int n_in,
                              void* d_out, int out_size, void* d_ws, size_t ws_size,
                              hipStream_t stream) {
    const int*   batch_nodes = (const int*)d_in[0];
    const int*   mp          = (const int*)d_in[1];
    const int*   edge_dst    = (const int*)d_in[2];
    const float* feat        = (const float*)d_in[3];
    const float* W_i         = (const float*)d_in[4];
    const float* W_p         = (const float*)d_in[5];
    const float* attn        = (const float*)d_in[6];
    const float* W_th        = (const float*)d_in[7];
    const float* W_gate      = (const float*)d_in[8];
    const float* b_gate      = (const float*)d_in[9];
    float* out = (float*)d_out;

    const int B = in_sizes[0];
    const int E = in_sizes[2];
    const int N = in_sizes[3] / 128;
    const int nb_scan = (N + 255) / 256;   // 391 for N=100000 (<=512)

    char* w = (char*)d_ws;
    auto alloc = [&](size_t bytes) -> void* {
        void* p = (void*)w;
        w += (bytes + 255) & ~(size_t)255;
        return p;
    };
    float* WT        = (float*)alloc(256 * 64 * sizeof(float));
    float* edata     = (float*)alloc((size_t)E * 64 * sizeof(float));
    float* logits    = (float*)alloc((size_t)E * 8 * sizeof(float));
    int*   mult      = (int*)  alloc((size_t)N * sizeof(int));
    int*   count     = (int*)  alloc((size_t)N * sizeof(int));
    int*   excl      = (int*)  alloc((size_t)N * sizeof(int));
    int*   offsets   = (int*)  alloc((size_t)(N + 1) * sizeof(int));
    int*   cursor    = (int*)  alloc((size_t)N * sizeof(int));
    int*   partials  = (int*)  alloc(512 * sizeof(int));
    int*   blockoff  = (int*)  alloc(512 * sizeof(int));
    int*   csr       = (int*)  alloc((size_t)E * sizeof(int));
    float* node_ft   = (float*)alloc((size_t)N * 512 * sizeof(float));
    float* gate_part = (float*)alloc(1024 * 8 * sizeof(float));
    float* gate      = (float*)alloc(256);

    hipMemsetAsync(mult, 0, (size_t)N * sizeof(int), stream);
    hipMemsetAsync(count, 0, (size_t)N * sizeof(int), stream);
    hipMemsetAsync(gate_part, 0, 1024 * 8 * sizeof(float), stream);

    k_transpose<<<64, 256, 0, stream>>>(W_i, W_p, WT);
    k_count<<<(B + 255) / 256, 256, 0, stream>>>(batch_nodes, mult, B);
    k_hist<<<(E + 255) / 256, 256, 0, stream>>>(edge_dst, mult, count, E);
    k_scan1<<<nb_scan, 256, 0, stream>>>(count, excl, partials, N);
    k_scan2<<<1, 512, 0, stream>>>(partials, blockoff, offsets, nb_scan, N);
    k_scan3<<<nb_scan, 256, 0, stream>>>(excl, blockoff, offsets, cursor, N);
    k_scatter<<<(E + 255) / 256, 256, 0, stream>>>(edge_dst, mult, cursor, csr, E);

    const int* pEc = offsets + N;
    k_edata<<<(E + 63) / 64, 256, 0, stream>>>(csr, pEc, mp, feat, WT, edata);
    k_logits<<<(E + 3) / 4, 256, 0, stream>>>(edata, attn, W_th, pEc, logits);
    k_node_agg<<<(N + 3) / 4, 256, 0, stream>>>(edata, logits, offsets, mult,
                                                W_gate, node_ft, gate_part, N);
    k_gatefinal<<<1, 256, 0, stream>>>(gate_part, b_gate, gate, B);
    k_output<<<(B * 128 + 255) / 256, 256, 0, stream>>>(node_ft, batch_nodes, gate, out, B);
}

// Round 3
// 363.068 us; speedup vs baseline: 2.7933x; 1.1044x over previous
//
#include <hip/hip_runtime.h>
#include <cstdint>
#include <cstddef>

// N=100000, E=300000, B=50000, L=4, D_EMB=128, D_HID=64, H=8. fp32 in/out.
// R3: linearity refactor. edata[e] = Yi[r0]+Yi[r3]+Yp[r1]+Yp[r2] with
// Y = feat @ [Wi;Wp].T  (dense MFMA split-bf16 GEMM, Y stored bf16).
// Logits via per-node projections P[n,16] = {Yi[n].attn_h, Yp[n].attn_h}.
// Per-edge work is pure gather. node_ft stored bf16 (only flagged rows).

typedef __attribute__((ext_vector_type(8))) short bf16x8;
typedef __attribute__((ext_vector_type(4))) float f32x4;

__device__ __forceinline__ unsigned short f2bf(float f) {
    unsigned u = __float_as_uint(f);
    unsigned r = u + 0x7fffu + ((u >> 16) & 1u);
    return (unsigned short)(r >> 16);
}
__device__ __forceinline__ float bf2f(unsigned short h) {
    return __uint_as_float((unsigned)h << 16);
}

// ---------------------------------------------------------------------------
// Pack B = [Wi;Wp].T (K=128 x N=128) into MFMA B-frag order, split hi/lo bf16.
// pack[(s*8+c)*512 + L*8 + j] = B[k][n], k=s*32+(L>>4)*8+j, n=c*16+(L&15).
__global__ __launch_bounds__(256) void k_prepW(
    const float* __restrict__ Wi, const float* __restrict__ Wp,
    unsigned short* __restrict__ Whi, unsigned short* __restrict__ Wlo) {
    int t = blockIdx.x * 256 + threadIdx.x;
    if (t >= 16384) return;
    int j = t & 7, L = (t >> 3) & 63, c = (t >> 9) & 7, s = t >> 12;
    int k = s * 32 + (L >> 4) * 8 + j;
    int n = c * 16 + (L & 15);
    float v = (n < 64) ? Wi[n * 128 + k] : Wp[(n - 64) * 128 + k];
    unsigned short h = f2bf(v);
    Whi[t] = h;
    Wlo[t] = f2bf(v - bf2f(h));
}

// ---------------------------------------------------------------------------
// Dense GEMM: Ybf[M x 128] = feat[M x 128] @ B, split-bf16 (3 MFMA per tile).
// Block = 4 waves; wave w does rows R0..R0+15, all 128 cols (8 col-tiles).
__global__ __launch_bounds__(256) void k_dense(
    const float* __restrict__ feat, const unsigned short* __restrict__ Whi,
    const unsigned short* __restrict__ Wlo, unsigned short* __restrict__ Ybf, int M) {
    int wave = threadIdx.x >> 6;
    int L = threadIdx.x & 63;
    int m = L & 15, q = L >> 4;
    int R0 = blockIdx.x * 64 + wave * 16;

    f32x4 acc[8];
#pragma unroll
    for (int c = 0; c < 8; ++c) acc[c] = (f32x4){0.f, 0.f, 0.f, 0.f};

    int rowc = R0 + m; if (rowc > M - 1) rowc = M - 1;
    const float* arow = feat + (size_t)rowc * 128;

    for (int s = 0; s < 4; ++s) {
        const float4* ap = (const float4*)(arow + s * 32 + q * 8);
        float4 a0 = ap[0], a1 = ap[1];
        float av[8] = {a0.x, a0.y, a0.z, a0.w, a1.x, a1.y, a1.z, a1.w};
        bf16x8 ahi, alo;
#pragma unroll
        for (int j = 0; j < 8; ++j) {
            unsigned short h = f2bf(av[j]);
            ahi[j] = (short)h;
            alo[j] = (short)f2bf(av[j] - bf2f(h));
        }
#pragma unroll
        for (int c = 0; c < 8; ++c) {
            const bf16x8 bh = *(const bf16x8*)(Whi + ((s * 8 + c) * 512 + L * 8));
            const bf16x8 bl = *(const bf16x8*)(Wlo + ((s * 8 + c) * 512 + L * 8));
            acc[c] = __builtin_amdgcn_mfma_f32_16x16x32_bf16(ahi, bh, acc[c], 0, 0, 0);
            acc[c] = __builtin_amdgcn_mfma_f32_16x16x32_bf16(ahi, bl, acc[c], 0, 0, 0);
            acc[c] = __builtin_amdgcn_mfma_f32_16x16x32_bf16(alo, bh, acc[c], 0, 0, 0);
        }
    }
    // C/D layout: col = lane&15, row = (lane>>4)*4 + reg
#pragma unroll
    for (int c = 0; c < 8; ++c) {
#pragma unroll
        for (int r = 0; r < 4; ++r) {
            int row = R0 + q * 4 + r;
            if (row < M) Ybf[(size_t)row * 128 + c * 16 + m] = f2bf(acc[c][r]);
        }
    }
}

// ---------------------------------------------------------------------------
// P[n,i] = Yi[n].attn_i (i=0..7), P[n,8+i] = Yp[n].attn_i. One wave per node.
__global__ __launch_bounds__(256) void k_P(
    const unsigned short* __restrict__ Ybf, const float* __restrict__ attn,
    float* __restrict__ P, int N) {
    int n = blockIdx.x * 4 + (threadIdx.x >> 6);
    int lane = threadIdx.x & 63;
    if (n >= N) return;
    const unsigned short* yr = Ybf + (size_t)n * 128;
    float y0 = bf2f(yr[2 * lane]), y1 = bf2f(yr[2 * lane + 1]);
    int d0 = (2 * lane) & 63, d1 = (2 * lane + 1) & 63;
#pragma unroll
    for (int i = 0; i < 8; ++i) {
        float p = y0 * attn[i * 64 + d0] + y1 * attn[i * 64 + d1];
#pragma unroll
        for (int o = 1; o < 32; o <<= 1) p += __shfl_xor(p, o);
        if (lane == 0)  P[n * 16 + i] = p;
        if (lane == 32) P[n * 16 + 8 + i] = p;
    }
}

// ---------------------------------------------------------------------------
// mult[n] = multiplicity of n in batch_nodes
__global__ __launch_bounds__(256) void k_count(
    const int* __restrict__ batch_nodes, int* __restrict__ mult, int B) {
    int i = blockIdx.x * 256 + threadIdx.x;
    if (i < B) atomicAdd(&mult[batch_nodes[i]], 1);
}

// count[d] = #incoming edges for flagged d
__global__ __launch_bounds__(256) void k_hist(
    const int* __restrict__ edge_dst, const int* __restrict__ mult,
    int* __restrict__ count, int E) {
    int e = blockIdx.x * 256 + threadIdx.x;
    if (e >= E) return;
    int d = edge_dst[e];
    if (mult[d] > 0) atomicAdd(&count[d], 1);
}

// exclusive scan of count -> offsets[0..N], offsets[N]=Ec
__global__ __launch_bounds__(256) void k_scan1(
    const int* __restrict__ count, int* __restrict__ excl, int* __restrict__ partials, int N) {
    __shared__ int lds[256];
    int t = threadIdx.x, i = blockIdx.x * 256 + t;
    int c = (i < N) ? count[i] : 0;
    lds[t] = c; __syncthreads();
    for (int o = 1; o < 256; o <<= 1) {
        int v = (t >= o) ? lds[t - o] : 0;
        __syncthreads(); lds[t] += v; __syncthreads();
    }
    if (i < N) excl[i] = lds[t] - c;
    if (t == 255) partials[blockIdx.x] = lds[255];
}
__global__ __launch_bounds__(512) void k_scan2(
    const int* __restrict__ partials, int* __restrict__ blockoff,
    int* __restrict__ offsets, int nb, int N) {
    __shared__ int lds[512];
    int t = threadIdx.x;
    int c = (t < nb) ? partials[t] : 0;
    lds[t] = c; __syncthreads();
    for (int o = 1; o < 512; o <<= 1) {
        int v = (t >= o) ? lds[t - o] : 0;
        __syncthreads(); lds[t] += v; __syncthreads();
    }
    if (t < nb) blockoff[t] = lds[t] - c;
    if (t == nb - 1) offsets[N] = lds[t];
}
__global__ __launch_bounds__(256) void k_scan3(
    const int* __restrict__ excl, const int* __restrict__ blockoff,
    int* __restrict__ offsets, int* __restrict__ cursor, int N) {
    int i = blockIdx.x * 256 + threadIdx.x;
    if (i < N) {
        int o = excl[i] + blockoff[i >> 8];
        offsets[i] = o; cursor[i] = o;
    }
}

// csr[pos] = edge id grouped by flagged dst
__global__ __launch_bounds__(256) void k_scatter(
    const int* __restrict__ edge_dst, const int* __restrict__ mult,
    int* __restrict__ cursor, int* __restrict__ csr, int E) {
    int e = blockIdx.x * 256 + threadIdx.x;
    if (e >= E) return;
    int d = edge_dst[e];
    if (mult[d] > 0) {
        int pos = atomicAdd(&cursor[d], 1);
        csr[pos] = e;
    }
}

// ---------------------------------------------------------------------------
// Per csr slot i: gather P rows -> logits[i,8] (lrelu'd), copy mp -> mpc.
// 8 lanes per edge (h = lane&7).
__global__ __launch_bounds__(256) void k_logits(
    const int* __restrict__ csr, const int* __restrict__ pEc,
    const int* __restrict__ mp, const float* __restrict__ P,
    const float* __restrict__ Wth, float* __restrict__ logits,
    int4* __restrict__ mpc) {
    int Ec = *pEc;
    int i = blockIdx.x * 32 + (threadIdx.x >> 3);
    if (i >= Ec) return;
    int h = threadIdx.x & 7;
    int e = csr[i];
    int4 rows = *(const int4*)(mp + (size_t)e * 4);
    float s = P[rows.x * 16 + h] + P[rows.w * 16 + h]
            + P[rows.y * 16 + 8 + h] + P[rows.z * 16 + 8 + h];
    int gbase = threadIdx.x & ~7;
    float l = 0.f;
#pragma unroll
    for (int j = 0; j < 8; ++j) {
        float sj = __shfl(s, gbase + j);
        l += Wth[h * 8 + j] * sj;
    }
    l = l > 0.f ? l : 0.01f * l;
    logits[(size_t)i * 8 + h] = l;
    if (h == 0) mpc[i] = rows;
}

// ---------------------------------------------------------------------------
// Per flagged node: 2-pass softmax + aggregation building edata from Ybf.
// One wave per node, lane = d. Writes nftb (bf16) once; fused gate dot.
__global__ __launch_bounds__(256) void k_node_agg(
    const unsigned short* __restrict__ Ybf, const float* __restrict__ logits,
    const int4* __restrict__ mpc, const int* __restrict__ offsets,
    const int* __restrict__ mult, const float* __restrict__ Wg,
    unsigned short* __restrict__ nftb, float* __restrict__ gate_part, int N) {
    int n = blockIdx.x * 4 + (threadIdx.x >> 6);
    int lane = threadIdx.x & 63;
    if (n >= N) return;
    int m = mult[n];
    if (m == 0) return;
    int beg = offsets[n], end = offsets[n + 1];

    float mx[8];
#pragma unroll
    for (int h = 0; h < 8; ++h) mx[h] = -1e30f;
    for (int j = beg; j < end; ++j) {
        const float4* lp = (const float4*)(logits + (size_t)j * 8);
        float4 l0 = lp[0], l1 = lp[1];
        mx[0] = fmaxf(mx[0], l0.x); mx[1] = fmaxf(mx[1], l0.y);
        mx[2] = fmaxf(mx[2], l0.z); mx[3] = fmaxf(mx[3], l0.w);
        mx[4] = fmaxf(mx[4], l1.x); mx[5] = fmaxf(mx[5], l1.y);
        mx[6] = fmaxf(mx[6], l1.z); mx[7] = fmaxf(mx[7], l1.w);
    }
    float den[8], acc[8];
#pragma unroll
    for (int h = 0; h < 8; ++h) { den[h] = 0.f; acc[h] = 0.f; }
    for (int j = beg; j < end; ++j) {
        const float4* lp = (const float4*)(logits + (size_t)j * 8);
        float4 l0 = lp[0], l1 = lp[1];
        int4 rows = mpc[j];
        float ed = bf2f(Ybf[(size_t)rows.x * 128 + lane])
                 + bf2f(Ybf[(size_t)rows.w * 128 + lane])
                 + bf2f(Ybf[(size_t)rows.y * 128 + 64 + lane])
                 + bf2f(Ybf[(size_t)rows.z * 128 + 64 + lane]);
        float w0 = __expf(l0.x - mx[0]), w1 = __expf(l0.y - mx[1]);
        float w2 = __expf(l0.z - mx[2]), w3 = __expf(l0.w - mx[3]);
        float w4 = __expf(l1.x - mx[4]), w5 = __expf(l1.y - mx[5]);
        float w6 = __expf(l1.z - mx[6]), w7 = __expf(l1.w - mx[7]);
        den[0] += w0; den[1] += w1; den[2] += w2; den[3] += w3;
        den[4] += w4; den[5] += w5; den[6] += w6; den[7] += w7;
        acc[0] += w0 * ed; acc[1] += w1 * ed; acc[2] += w2 * ed; acc[3] += w3 * ed;
        acc[4] += w4 * ed; acc[5] += w5 * ed; acc[6] += w6 * ed; acc[7] += w7 * ed;
    }
#pragma unroll
    for (int h = 0; h < 8; ++h) {
        float r = (end > beg) ? 1.f / den[h] : 0.f;
        acc[h] *= r;
    }

    unsigned short* base = nftb + (size_t)n * 512;
#pragma unroll
    for (int h = 0; h < 8; ++h) base[h * 64 + lane] = f2bf(acc[h]);

    float wg = Wg[lane];
    float myg = 0.f;
#pragma unroll
    for (int h = 0; h < 8; ++h) {
        float p = acc[h] * wg;
#pragma unroll
        for (int o = 32; o > 0; o >>= 1) p += __shfl_xor(p, o);
        if (lane == h) myg = p;
    }
    if (lane < 8)
        atomicAdd(&gate_part[(blockIdx.x & 1023) * 8 + lane], (float)m * myg);
}

// gate[h] = sum(gate_part)/B + b_gate
__global__ __launch_bounds__(256) void k_gatefinal(
    const float* __restrict__ gate_part, const float* __restrict__ b_gate,
    float* __restrict__ gate, int B) {
    __shared__ float lds[256];
    int t = threadIdx.x;
    int h = t & 7, g = t >> 3;
    float s = 0.f;
    for (int b = g; b < 1024; b += 32) s += gate_part[b * 8 + h];
    lds[t] = s; __syncthreads();
    if (t < 8) {
        float tot = 0.f;
        for (int gg = 0; gg < 32; ++gg) tot += lds[gg * 8 + t];
        gate[t] = tot / (float)B + b_gate[0];
    }
}

// out[b, h*64+d] = nftb[batch_nodes[b]] * gate[h]
__global__ __launch_bounds__(256) void k_output(
    const unsigned short* __restrict__ nftb, const int* __restrict__ batch_nodes,
    const float* __restrict__ gate, float* __restrict__ out, int B) {
    int idx = blockIdx.x * 256 + threadIdx.x;
    int total = B * 128;
    if (idx >= total) return;
    int b = idx >> 7;
    int rem4 = idx & 127;
    int h = rem4 >> 4;
    int n = batch_nodes[b];
    ushort4 v = *(const ushort4*)(nftb + (size_t)n * 512 + rem4 * 4);
    float g = gate[h];
    float4 o;
    o.x = bf2f(v.x) * g; o.y = bf2f(v.y) * g;
    o.z = bf2f(v.z) * g; o.w = bf2f(v.w) * g;
    *(float4*)(out + (size_t)idx * 4) = o;
}

// ---------------------------------------------------------------------------
extern "C" void kernel_launch(void* const* d_in, const int* in_sizes, int n_in,
                              void* d_out, int out_size, void* d_ws, size_t ws_size,
                              hipStream_t stream) {
    const int*   batch_nodes = (const int*)d_in[0];
    const int*   mp          = (const int*)d_in[1];
    const int*   edge_dst    = (const int*)d_in[2];
    const float* feat        = (const float*)d_in[3];
    const float* W_i         = (const float*)d_in[4];
    const float* W_p         = (const float*)d_in[5];
    const float* attn        = (const float*)d_in[6];
    const float* W_th        = (const float*)d_in[7];
    const float* W_gate      = (const float*)d_in[8];
    const float* b_gate      = (const float*)d_in[9];
    float* out = (float*)d_out;

    const int B = in_sizes[0];
    const int E = in_sizes[2];
    const int N = in_sizes[3] / 128;
    const int nb_scan = (N + 255) / 256;

    char* w = (char*)d_ws;
    auto alloc = [&](size_t bytes) -> void* {
        void* p = (void*)w;
        w += (bytes + 255) & ~(size_t)255;
        return p;
    };
    unsigned short* Whi = (unsigned short*)alloc(16384 * 2);
    unsigned short* Wlo = (unsigned short*)alloc(16384 * 2);
    unsigned short* Ybf = (unsigned short*)alloc((size_t)N * 128 * 2);   // 25.6 MB
    float* P            = (float*)alloc((size_t)N * 16 * 4);             // 6.4 MB
    float* logits       = (float*)alloc((size_t)E * 8 * 4);              // 9.6 MB
    int4*  mpc          = (int4*)alloc((size_t)E * 16);                  // 4.8 MB
    int*   mult         = (int*)alloc((size_t)N * 4);
    int*   count        = (int*)alloc((size_t)N * 4);
    int*   excl         = (int*)alloc((size_t)N * 4);
    int*   offsets      = (int*)alloc((size_t)(N + 1) * 4);
    int*   cursor       = (int*)alloc((size_t)N * 4);
    int*   partials     = (int*)alloc(512 * 4);
    int*   blockoff     = (int*)alloc(512 * 4);
    int*   csr          = (int*)alloc((size_t)E * 4);
    unsigned short* nftb = (unsigned short*)alloc((size_t)N * 512 * 2);  // 102.4 MB
    float* gate_part    = (float*)alloc(1024 * 8 * 4);
    float* gate         = (float*)alloc(256);

    hipMemsetAsync(mult, 0, (size_t)N * 4, stream);
    hipMemsetAsync(count, 0, (size_t)N * 4, stream);
    hipMemsetAsync(gate_part, 0, 1024 * 8 * 4, stream);

    k_prepW<<<64, 256, 0, stream>>>(W_i, W_p, Whi, Wlo);
    k_dense<<<(N + 63) / 64, 256, 0, stream>>>(feat, Whi, Wlo, Ybf, N);
    k_P<<<(N + 3) / 4, 256, 0, stream>>>(Ybf, attn, P, N);

    k_count<<<(B + 255) / 256, 256, 0, stream>>>(batch_nodes, mult, B);
    k_hist<<<(E + 255) / 256, 256, 0, stream>>>(edge_dst, mult, count, E);
    k_scan1<<<nb_scan, 256, 0, stream>>>(count, excl, partials, N);
    k_scan2<<<1, 512, 0, stream>>>(partials, blockoff, offsets, nb_scan, N);
    k_scan3<<<nb_scan, 256, 0, stream>>>(excl, blockoff, offsets, cursor, N);
    k_scatter<<<(E + 255) / 256, 256, 0, stream>>>(edge_dst, mult, cursor, csr, E);

    const int* pEc = offsets + N;
    k_logits<<<(E + 31) / 32, 256, 0, stream>>>(csr, pEc, mp, P, W_th, logits, mpc);
    k_node_agg<<<(N + 3) / 4, 256, 0, stream>>>(Ybf, logits, mpc, offsets, mult,
                                                W_gate, nftb, gate_part, N);
    k_gatefinal<<<1, 256, 0, stream>>>(gate_part, b_gate, gate, B);
    k_output<<<(B * 128 + 255) / 256, 256, 0, stream>>>(nftb, batch_nodes, gate, out, B);
}